// Round 9
// baseline (207.543 us; speedup 1.0000x reference)
//
#include <hip/hip_runtime.h>

#define N_NODES 20000
#define N_EDGES 640000
#define F 128
#define CAP 128          // max in-degree; deg ~ Binomial(640K, 1/20K), P(deg>=128) ~ 1e-37
#define GEMM_BLOCKS (N_NODES / 32)     // 625
#define BUCKET_BLOCKS (N_EDGES / 256)  // 2500

// HISTORY:
//  r2/r3: fused GEMM+proj epilogue spilled (64-VGPR cap; VGPR=256 + 565 MB scratch).
//  r4: de-fused: 218 us. r5: gather-into-GEMM fusion -> occ 22.6%: 227 (revert).
//  r6: mean-linearity reorder (GEMM first): 215. r7: gemm1+bucket merge: 213.
//  r8: uint16 bucket + slice-partitioned agg (4 x 32-float slices, blockIdx%8 XCD
//      swizzle -> slice fits 4 MB XCD L2): 203 us, absmax 1.5e-5.
//  r9: fuse 128->2 projection into slice_agg2 epilogue via per-slice partial dot +
//      atomicAdd (out zeroed up front) -> removes final_kernel + 20 MB h round-trip.

// ---------------------------------------------------------------------------
// Merged: blocks [0,625) y = A @ W (proven 44-VGPR tile); blocks [625,3125)
// scatter edges into per-destination uint16 buckets. Independent halves.
// ---------------------------------------------------------------------------
__global__ __launch_bounds__(256)
void gemm_bucket_kernel(const float* __restrict__ A, const float* __restrict__ W,
                        float* __restrict__ C,
                        const int* __restrict__ src, const int* __restrict__ dst,
                        int* __restrict__ cnt, unsigned short* __restrict__ bucket) {
    __shared__ float As[32][F + 4];
    int tid = threadIdx.x;

    if (blockIdx.x >= GEMM_BLOCKS) {
        int e = (blockIdx.x - GEMM_BLOCKS) * 256 + tid;
        if (e < N_EDGES) {
            int d = dst[e];
            int pos = atomicAdd(&cnt[d], 1);
            if (pos < CAP) bucket[(size_t)d * CAP + pos] = (unsigned short)src[e];
        }
        return;
    }

    int row0 = blockIdx.x * 32;
    const float4* A4 = (const float4*)(A + (size_t)row0 * F);
    for (int i = tid; i < 32 * 32; i += 256) {
        float4 v = A4[i];
        int r = i >> 5, c4 = (i & 31) * 4;
        *(float4*)&As[r][c4] = v;
    }
    __syncthreads();

    int tx = tid & 31, ty = tid >> 5;
    int c0 = tx * 4, r0 = ty * 4;
    float acc[4][4] = {};

    for (int k = 0; k < F; k += 4) {
        float4 a4[4];
#pragma unroll
        for (int i = 0; i < 4; ++i) a4[i] = *(const float4*)&As[r0 + i][k];
#pragma unroll
        for (int u = 0; u < 4; ++u) {
            float4 w = *(const float4*)(W + (size_t)(k + u) * F + c0);
#pragma unroll
            for (int i = 0; i < 4; ++i) {
                float a = (u == 0) ? a4[i].x : (u == 1) ? a4[i].y : (u == 2) ? a4[i].z : a4[i].w;
                acc[i][0] += a * w.x;
                acc[i][1] += a * w.y;
                acc[i][2] += a * w.z;
                acc[i][3] += a * w.w;
            }
        }
    }

#pragma unroll
    for (int i = 0; i < 4; ++i) {
        float4 o;
        o.x = acc[i][0]; o.y = acc[i][1]; o.z = acc[i][2]; o.w = acc[i][3];
        *(float4*)(C + (size_t)(row0 + r0 + i) * F + c0) = o;
    }
}

// ---------------------------------------------------------------------------
// Plain GEMM (layer 2): C = A @ W.
// ---------------------------------------------------------------------------
__global__ __launch_bounds__(256)
void gemm_kernel(const float* __restrict__ A, const float* __restrict__ W,
                 float* __restrict__ C) {
    __shared__ float As[32][F + 4];
    int tid  = threadIdx.x;
    int row0 = blockIdx.x * 32;

    const float4* A4 = (const float4*)(A + (size_t)row0 * F);
    for (int i = tid; i < 32 * 32; i += 256) {
        float4 v = A4[i];
        int r = i >> 5, c4 = (i & 31) * 4;
        *(float4*)&As[r][c4] = v;
    }
    __syncthreads();

    int tx = tid & 31, ty = tid >> 5;
    int c0 = tx * 4, r0 = ty * 4;
    float acc[4][4] = {};

    for (int k = 0; k < F; k += 4) {
        float4 a4[4];
#pragma unroll
        for (int i = 0; i < 4; ++i) a4[i] = *(const float4*)&As[r0 + i][k];
#pragma unroll
        for (int u = 0; u < 4; ++u) {
            float4 w = *(const float4*)(W + (size_t)(k + u) * F + c0);
#pragma unroll
            for (int i = 0; i < 4; ++i) {
                float a = (u == 0) ? a4[i].x : (u == 1) ? a4[i].y : (u == 2) ? a4[i].z : a4[i].w;
                acc[i][0] += a * w.x;
                acc[i][1] += a * w.y;
                acc[i][2] += a * w.z;
                acc[i][3] += a * w.w;
            }
        }
    }

#pragma unroll
    for (int i = 0; i < 4; ++i) {
        float4 o;
        o.x = acc[i][0]; o.y = acc[i][1]; o.z = acc[i][2]; o.w = acc[i][3];
        *(float4*)(C + (size_t)(row0 + r0 + i) * F + c0) = o;
    }
}

// ---------------------------------------------------------------------------
// Slice-partitioned gather + bias + relu (layer 1):
//   out[n, slice] = relu(mean_{j in nbrs(n)} y[j, slice] + b[slice])
// Grid 20000 x 256. g = bid%8 -> XCD heuristic; slice = g&3 (2.56 MB per
// slice fits the 4 MB XCD L2). Wave = 8 rows x 8 float4-cols per gather.
// ---------------------------------------------------------------------------
__global__ __launch_bounds__(256)
void slice_agg_kernel(const float* __restrict__ y, const int* __restrict__ cnt,
                      const unsigned short* __restrict__ bucket,
                      const float* __restrict__ b, float* __restrict__ out) {
    int bid   = blockIdx.x;
    int g     = bid & 7;
    int i     = bid >> 3;
    int slice = g & 3;
    int j     = i * 2 + (g >> 2);
    int wave  = threadIdx.x >> 6;
    int lane  = threadIdx.x & 63;
    int node  = j * 4 + wave;
    int r     = lane >> 3;
    int c4    = lane & 7;

    int deg = cnt[node];
    const unsigned short* lst = bucket + (size_t)node * CAP;
    const float4* f4 = (const float4*)y + slice * 8 + c4;

    float4 acc; acc.x = acc.y = acc.z = acc.w = 0.f;
    int nfull = deg >> 3;
    int c = 0;
    for (; c + 4 <= nfull; c += 4) {
        int base = (c << 3) + r;
        int i0 = lst[base];
        int i1 = lst[base + 8];
        int i2 = lst[base + 16];
        int i3 = lst[base + 24];
        float4 v0 = f4[(size_t)i0 * 32];
        float4 v1 = f4[(size_t)i1 * 32];
        float4 v2 = f4[(size_t)i2 * 32];
        float4 v3 = f4[(size_t)i3 * 32];
        acc.x += (v0.x + v1.x) + (v2.x + v3.x);
        acc.y += (v0.y + v1.y) + (v2.y + v3.y);
        acc.z += (v0.z + v1.z) + (v2.z + v3.z);
        acc.w += (v0.w + v1.w) + (v2.w + v3.w);
    }
    for (; c < nfull; ++c) {
        int idx = lst[(c << 3) + r];
        float4 v = f4[(size_t)idx * 32];
        acc.x += v.x; acc.y += v.y; acc.z += v.z; acc.w += v.w;
    }
    if (r < (deg & 7)) {
        int idx = lst[(nfull << 3) + r];
        float4 v = f4[(size_t)idx * 32];
        acc.x += v.x; acc.y += v.y; acc.z += v.z; acc.w += v.w;
    }

#pragma unroll
    for (int off = 8; off < 64; off <<= 1) {
        acc.x += __shfl_xor(acc.x, off);
        acc.y += __shfl_xor(acc.y, off);
        acc.z += __shfl_xor(acc.z, off);
        acc.w += __shfl_xor(acc.w, off);
    }

    if (r == 0) {
        float inv = 1.0f / fmaxf((float)deg, 1.0f);
        float4 bv = ((const float4*)b)[slice * 8 + c4];
        float4 o;
        o.x = fmaxf(acc.x * inv + bv.x, 0.f);
        o.y = fmaxf(acc.y * inv + bv.y, 0.f);
        o.z = fmaxf(acc.z * inv + bv.z, 0.f);
        o.w = fmaxf(acc.w * inv + bv.w, 0.f);
        ((float4*)out)[(size_t)node * 32 + slice * 8 + c4] = o;
    }
}

// ---------------------------------------------------------------------------
// Layer-2 slice agg with FUSED 128->2 projection:
//   h_s = relu(mean(y)[n, slice] + b2[slice])  (in registers)
//   atomicAdd(out[n,0..1], h_s . W3[slice rows])   (+ b3 from slice 0)
// out must be pre-zeroed. Epilogue is ~12 live regs -> no spill risk.
// ---------------------------------------------------------------------------
__global__ __launch_bounds__(256)
void slice_agg_proj_kernel(const float* __restrict__ y, const int* __restrict__ cnt,
                           const unsigned short* __restrict__ bucket,
                           const float* __restrict__ b, const float* __restrict__ W3,
                           const float* __restrict__ b3, float* __restrict__ out) {
    int bid   = blockIdx.x;
    int g     = bid & 7;
    int i     = bid >> 3;
    int slice = g & 3;
    int j     = i * 2 + (g >> 2);
    int wave  = threadIdx.x >> 6;
    int lane  = threadIdx.x & 63;
    int node  = j * 4 + wave;
    int r     = lane >> 3;
    int c4    = lane & 7;

    int deg = cnt[node];
    const unsigned short* lst = bucket + (size_t)node * CAP;
    const float4* f4 = (const float4*)y + slice * 8 + c4;

    float4 acc; acc.x = acc.y = acc.z = acc.w = 0.f;
    int nfull = deg >> 3;
    int c = 0;
    for (; c + 4 <= nfull; c += 4) {
        int base = (c << 3) + r;
        int i0 = lst[base];
        int i1 = lst[base + 8];
        int i2 = lst[base + 16];
        int i3 = lst[base + 24];
        float4 v0 = f4[(size_t)i0 * 32];
        float4 v1 = f4[(size_t)i1 * 32];
        float4 v2 = f4[(size_t)i2 * 32];
        float4 v3 = f4[(size_t)i3 * 32];
        acc.x += (v0.x + v1.x) + (v2.x + v3.x);
        acc.y += (v0.y + v1.y) + (v2.y + v3.y);
        acc.z += (v0.z + v1.z) + (v2.z + v3.z);
        acc.w += (v0.w + v1.w) + (v2.w + v3.w);
    }
    for (; c < nfull; ++c) {
        int idx = lst[(c << 3) + r];
        float4 v = f4[(size_t)idx * 32];
        acc.x += v.x; acc.y += v.y; acc.z += v.z; acc.w += v.w;
    }
    if (r < (deg & 7)) {
        int idx = lst[(nfull << 3) + r];
        float4 v = f4[(size_t)idx * 32];
        acc.x += v.x; acc.y += v.y; acc.z += v.z; acc.w += v.w;
    }

#pragma unroll
    for (int off = 8; off < 64; off <<= 1) {
        acc.x += __shfl_xor(acc.x, off);
        acc.y += __shfl_xor(acc.y, off);
        acc.z += __shfl_xor(acc.z, off);
        acc.w += __shfl_xor(acc.w, off);
    }

    // lanes 0-7 (r==0) each hold the full slice sums for features
    // slice*32 + c4*4 .. +3; compute h and the partial 128->2 dot.
    float inv = 1.0f / fmaxf((float)deg, 1.0f);
    float4 bv = ((const float4*)b)[slice * 8 + c4];
    float h0 = fmaxf(acc.x * inv + bv.x, 0.f);
    float h1 = fmaxf(acc.y * inv + bv.y, 0.f);
    float h2 = fmaxf(acc.z * inv + bv.z, 0.f);
    float h3 = fmaxf(acc.w * inv + bv.w, 0.f);
    int krow = slice * 32 + c4 * 4;     // W3 row index
    float2 w0 = ((const float2*)W3)[krow];
    float2 w1 = ((const float2*)W3)[krow + 1];
    float2 w2 = ((const float2*)W3)[krow + 2];
    float2 w3 = ((const float2*)W3)[krow + 3];
    float p0 = h0 * w0.x + h1 * w1.x + h2 * w2.x + h3 * w3.x;
    float p1 = h0 * w0.y + h1 * w1.y + h2 * w2.y + h3 * w3.y;
    // reduce over lanes 0..7 (stays within the group for off<8)
#pragma unroll
    for (int off = 1; off < 8; off <<= 1) {
        p0 += __shfl_xor(p0, off);
        p1 += __shfl_xor(p1, off);
    }
    if (lane == 0) {
        if (slice == 0) { p0 += b3[0]; p1 += b3[1]; }
        atomicAdd(out + (size_t)node * 2,     p0);
        atomicAdd(out + (size_t)node * 2 + 1, p1);
    }
}

// ---------------------------------------------------------------------------
extern "C" void kernel_launch(void* const* d_in, const int* in_sizes, int n_in,
                              void* d_out, int out_size, void* d_ws, size_t ws_size,
                              hipStream_t stream) {
    const float* x   = (const float*)d_in[0];
    const int*   ei  = (const int*)d_in[1];
    const int*   src = ei;
    const int*   dst = ei + N_EDGES;
    const float* W1 = (const float*)d_in[2];
    const float* b1 = (const float*)d_in[3];
    const float* W2 = (const float*)d_in[4];
    const float* b2 = (const float*)d_in[5];
    const float* W3 = (const float*)d_in[6];
    const float* b3 = (const float*)d_in[7];
    float* out = (float*)d_out;

    char* base = (char*)d_ws;
    size_t off = 0;
    auto take = [&](size_t bytes) -> char* {
        char* p = base + off;
        off += (bytes + 255) & ~(size_t)255;
        return p;
    };
    int*            cnt    = (int*)           take(N_NODES * sizeof(int));
    unsigned short* bucket = (unsigned short*)take((size_t)N_NODES * CAP * sizeof(unsigned short));
    float*          y      = (float*)         take((size_t)N_NODES * F * sizeof(float));
    float*          h      = (float*)         take((size_t)N_NODES * F * sizeof(float));

    hipMemsetAsync(cnt, 0, N_NODES * sizeof(int), stream);
    hipMemsetAsync(out, 0, (size_t)N_NODES * 2 * sizeof(float), stream);

    // layer 1 GEMM (y = x@W1) overlapped with uint16 bucket build
    gemm_bucket_kernel<<<GEMM_BLOCKS + BUCKET_BLOCKS, 256, 0, stream>>>(
        x, W1, y, src, dst, cnt, bucket);
    // h = relu(mean(y) + b1)
    slice_agg_kernel<<<N_NODES, 256, 0, stream>>>(y, cnt, bucket, b1, h);
    // y = h @ W2
    gemm_kernel<<<N_NODES / 32, 256, 0, stream>>>(h, W2, y);
    // out = relu(mean(y) + b2) @ W3 + b3   (projection fused, atomic accumulate)
    slice_agg_proj_kernel<<<N_NODES, 256, 0, stream>>>(y, cnt, bucket, b2, W3, b3, out);
}

// Round 10
// 187.361 us; speedup vs baseline: 1.1077x; 1.1077x over previous
//
#include <hip/hip_runtime.h>

#define N_NODES 20000
#define N_EDGES 640000
#define F 128
#define CAP 128          // max in-degree; deg ~ Binomial(640K, 1/20K), P(deg>=128) ~ 1e-37
#define GEMM_BLOCKS (N_NODES / 32)     // 625
#define BUCKET_BLOCKS (N_EDGES / 256)  // 2500

// HISTORY:
//  r2/r3: fused GEMM+proj epilogue spilled (64-VGPR cap; VGPR=256 + 565 MB scratch).
//  r4: de-fused: 218 us. r5: gather-into-GEMM fusion -> occ 22.6%: 227 (revert).
//  r6: mean-linearity reorder (GEMM first): 215. r7: gemm1+bucket merge: 213.
//  r8: uint16 bucket + slice-partitioned agg (4 x 32-float slices, blockIdx%8 XCD
//      swizzle -> slice fits 4 MB XCD L2): 203 us.
//  r9: proj fused into agg2 via atomicAdd: 207.5 (regression; atomics+extra memset
//      cost more than the 20 MB h round-trip). REVERTED.
//  r10: agg latency attack: (a) whole index list prefetched into registers
//       (1 int load/lane = 128 u16), per-chunk indices via __shfl (ALU) ->
//       removes the index-load hop; (b) 2 nodes per wave -> 2 independent
//       gather chains, up to 8 feature loads in flight, half the blocks.

// ---------------------------------------------------------------------------
// Merged: blocks [0,625) y = A @ W (proven 44-VGPR tile); blocks [625,3125)
// scatter edges into per-destination uint16 buckets. Independent halves.
// ---------------------------------------------------------------------------
__global__ __launch_bounds__(256)
void gemm_bucket_kernel(const float* __restrict__ A, const float* __restrict__ W,
                        float* __restrict__ C,
                        const int* __restrict__ src, const int* __restrict__ dst,
                        int* __restrict__ cnt, unsigned short* __restrict__ bucket) {
    __shared__ float As[32][F + 4];
    int tid = threadIdx.x;

    if (blockIdx.x >= GEMM_BLOCKS) {
        int e = (blockIdx.x - GEMM_BLOCKS) * 256 + tid;
        if (e < N_EDGES) {
            int d = dst[e];
            int pos = atomicAdd(&cnt[d], 1);
            if (pos < CAP) bucket[(size_t)d * CAP + pos] = (unsigned short)src[e];
        }
        return;
    }

    int row0 = blockIdx.x * 32;
    const float4* A4 = (const float4*)(A + (size_t)row0 * F);
    for (int i = tid; i < 32 * 32; i += 256) {
        float4 v = A4[i];
        int r = i >> 5, c4 = (i & 31) * 4;
        *(float4*)&As[r][c4] = v;
    }
    __syncthreads();

    int tx = tid & 31, ty = tid >> 5;
    int c0 = tx * 4, r0 = ty * 4;
    float acc[4][4] = {};

    for (int k = 0; k < F; k += 4) {
        float4 a4[4];
#pragma unroll
        for (int i = 0; i < 4; ++i) a4[i] = *(const float4*)&As[r0 + i][k];
#pragma unroll
        for (int u = 0; u < 4; ++u) {
            float4 w = *(const float4*)(W + (size_t)(k + u) * F + c0);
#pragma unroll
            for (int i = 0; i < 4; ++i) {
                float a = (u == 0) ? a4[i].x : (u == 1) ? a4[i].y : (u == 2) ? a4[i].z : a4[i].w;
                acc[i][0] += a * w.x;
                acc[i][1] += a * w.y;
                acc[i][2] += a * w.z;
                acc[i][3] += a * w.w;
            }
        }
    }

#pragma unroll
    for (int i = 0; i < 4; ++i) {
        float4 o;
        o.x = acc[i][0]; o.y = acc[i][1]; o.z = acc[i][2]; o.w = acc[i][3];
        *(float4*)(C + (size_t)(row0 + r0 + i) * F + c0) = o;
    }
}

// ---------------------------------------------------------------------------
// Plain GEMM (layer 2): C = A @ W.
// ---------------------------------------------------------------------------
__global__ __launch_bounds__(256)
void gemm_kernel(const float* __restrict__ A, const float* __restrict__ W,
                 float* __restrict__ C) {
    __shared__ float As[32][F + 4];
    int tid  = threadIdx.x;
    int row0 = blockIdx.x * 32;

    const float4* A4 = (const float4*)(A + (size_t)row0 * F);
    for (int i = tid; i < 32 * 32; i += 256) {
        float4 v = A4[i];
        int r = i >> 5, c4 = (i & 31) * 4;
        *(float4*)&As[r][c4] = v;
    }
    __syncthreads();

    int tx = tid & 31, ty = tid >> 5;
    int c0 = tx * 4, r0 = ty * 4;
    float acc[4][4] = {};

    for (int k = 0; k < F; k += 4) {
        float4 a4[4];
#pragma unroll
        for (int i = 0; i < 4; ++i) a4[i] = *(const float4*)&As[r0 + i][k];
#pragma unroll
        for (int u = 0; u < 4; ++u) {
            float4 w = *(const float4*)(W + (size_t)(k + u) * F + c0);
#pragma unroll
            for (int i = 0; i < 4; ++i) {
                float a = (u == 0) ? a4[i].x : (u == 1) ? a4[i].y : (u == 2) ? a4[i].z : a4[i].w;
                acc[i][0] += a * w.x;
                acc[i][1] += a * w.y;
                acc[i][2] += a * w.z;
                acc[i][3] += a * w.w;
            }
        }
    }

#pragma unroll
    for (int i = 0; i < 4; ++i) {
        float4 o;
        o.x = acc[i][0]; o.y = acc[i][1]; o.z = acc[i][2]; o.w = acc[i][3];
        *(float4*)(C + (size_t)(row0 + r0 + i) * F + c0) = o;
    }
}

// ---------------------------------------------------------------------------
// One node-slice gather with indices held in registers (packed = 2 u16/lane,
// lane l holds list positions 2l, 2l+1). Position p=(c<<3)+r lives in word
// p>>1 = (c<<2)+(r>>1), half p&1 = r&1. All shfls execute with full exec
// mask (deg is wave-uniform; the tail shfl is hoisted before the divergent
// guard because shfl from an inactive source lane is undefined).
// ---------------------------------------------------------------------------
__device__ __forceinline__ float4 slice_gather(const float4* __restrict__ fb,
                                               int packed, int deg, int r) {
    float4 acc; acc.x = acc.y = acc.z = acc.w = 0.f;
    int nchunks = deg >> 3;        // full 8-neighbor chunks
    int sh  = r >> 1;
    int sel = r & 1;
    int c = 0;
    for (; c + 4 <= nchunks; c += 4) {
        int w0 = __shfl(packed, (c << 2) + sh);
        int w1 = __shfl(packed, ((c + 1) << 2) + sh);
        int w2 = __shfl(packed, ((c + 2) << 2) + sh);
        int w3 = __shfl(packed, ((c + 3) << 2) + sh);
        int i0 = sel ? ((w0 >> 16) & 0xffff) : (w0 & 0xffff);
        int i1 = sel ? ((w1 >> 16) & 0xffff) : (w1 & 0xffff);
        int i2 = sel ? ((w2 >> 16) & 0xffff) : (w2 & 0xffff);
        int i3 = sel ? ((w3 >> 16) & 0xffff) : (w3 & 0xffff);
        float4 v0 = fb[(size_t)i0 * 32];
        float4 v1 = fb[(size_t)i1 * 32];
        float4 v2 = fb[(size_t)i2 * 32];
        float4 v3 = fb[(size_t)i3 * 32];
        acc.x += (v0.x + v1.x) + (v2.x + v3.x);
        acc.y += (v0.y + v1.y) + (v2.y + v3.y);
        acc.z += (v0.z + v1.z) + (v2.z + v3.z);
        acc.w += (v0.w + v1.w) + (v2.w + v3.w);
    }
    for (; c < nchunks; ++c) {
        int w = __shfl(packed, (c << 2) + sh);
        int idx = sel ? ((w >> 16) & 0xffff) : (w & 0xffff);
        float4 v = fb[(size_t)idx * 32];
        acc.x += v.x; acc.y += v.y; acc.z += v.z; acc.w += v.w;
    }
    int wt = __shfl(packed, (nchunks << 2) + sh);   // hoisted: full exec mask
    if (r < (deg & 7)) {
        int idx = sel ? ((wt >> 16) & 0xffff) : (wt & 0xffff);
        float4 v = fb[(size_t)idx * 32];
        acc.x += v.x; acc.y += v.y; acc.z += v.z; acc.w += v.w;
    }
    return acc;
}

// ---------------------------------------------------------------------------
// Slice-partitioned gather + bias + relu, TWO nodes per wave:
//   out[n, slice] = relu(mean_{j in nbrs(n)} y[j, slice] + b[slice])
// Grid 10000 x 256. g = bid%8 -> XCD heuristic; slice = g&3 (2.56 MB slice
// fits the 4 MB XCD L2). Wave = 8 rows x 8 float4-cols per gather instr;
// two independent gather chains per wave -> up to 8 loads in flight.
// ---------------------------------------------------------------------------
__global__ __launch_bounds__(256)
void slice_agg_kernel(const float* __restrict__ y, const int* __restrict__ cnt,
                      const unsigned short* __restrict__ bucket,
                      const float* __restrict__ b, float* __restrict__ out) {
    int bid   = blockIdx.x;
    int g     = bid & 7;
    int i     = bid >> 3;          // 0..1249
    int slice = g & 3;
    int jj    = i * 2 + (g >> 2);  // 0..2499
    int wave  = threadIdx.x >> 6;
    int lane  = threadIdx.x & 63;
    int node0 = jj * 8 + wave * 2;
    int node1 = node0 + 1;
    int r     = lane >> 3;
    int c4    = lane & 7;

    int deg0 = cnt[node0];
    int deg1 = cnt[node1];
    const unsigned short* lst0 = bucket + (size_t)node0 * CAP;
    const unsigned short* lst1 = bucket + (size_t)node1 * CAP;
    int packed0 = *(const int*)(lst0 + 2 * lane);
    int packed1 = *(const int*)(lst1 + 2 * lane);

    const float4* fb = (const float4*)y + slice * 8 + c4;   // row stride 32 float4

    int d0 = deg0 < CAP ? deg0 : CAP;
    int d1 = deg1 < CAP ? deg1 : CAP;
    float4 a0 = slice_gather(fb, packed0, d0, r);
    float4 a1 = slice_gather(fb, packed1, d1, r);

#pragma unroll
    for (int off = 8; off < 64; off <<= 1) {
        a0.x += __shfl_xor(a0.x, off);
        a0.y += __shfl_xor(a0.y, off);
        a0.z += __shfl_xor(a0.z, off);
        a0.w += __shfl_xor(a0.w, off);
        a1.x += __shfl_xor(a1.x, off);
        a1.y += __shfl_xor(a1.y, off);
        a1.z += __shfl_xor(a1.z, off);
        a1.w += __shfl_xor(a1.w, off);
    }

    if (r == 0) {   // lanes 0..7: lane == c4
        float4 bv = ((const float4*)b)[slice * 8 + c4];
        float inv0 = 1.0f / fmaxf((float)deg0, 1.0f);
        float4 o0;
        o0.x = fmaxf(a0.x * inv0 + bv.x, 0.f);
        o0.y = fmaxf(a0.y * inv0 + bv.y, 0.f);
        o0.z = fmaxf(a0.z * inv0 + bv.z, 0.f);
        o0.w = fmaxf(a0.w * inv0 + bv.w, 0.f);
        ((float4*)out)[(size_t)node0 * 32 + slice * 8 + c4] = o0;
        float inv1 = 1.0f / fmaxf((float)deg1, 1.0f);
        float4 o1;
        o1.x = fmaxf(a1.x * inv1 + bv.x, 0.f);
        o1.y = fmaxf(a1.y * inv1 + bv.y, 0.f);
        o1.z = fmaxf(a1.z * inv1 + bv.z, 0.f);
        o1.w = fmaxf(a1.w * inv1 + bv.w, 0.f);
        ((float4*)out)[(size_t)node1 * 32 + slice * 8 + c4] = o1;
    }
}

// ---------------------------------------------------------------------------
// out[N x 2] = h[N x 128] @ W3[128 x 2] + b3. One wave per node, shuffle
// reduce. Proven cheap (never in any top-5).
// ---------------------------------------------------------------------------
__global__ __launch_bounds__(256)
void final_kernel(const float* __restrict__ h, const float* __restrict__ W3,
                  const float* __restrict__ b3, float* __restrict__ out) {
    int wid  = (blockIdx.x * blockDim.x + threadIdx.x) >> 6;
    int lane = threadIdx.x & 63;
    if (wid >= N_NODES) return;
    float2 v = ((const float2*)h)[(size_t)wid * 64 + lane];
    float4 w = ((const float4*)W3)[lane];
    float a0 = v.x * w.x + v.y * w.z;
    float a1 = v.x * w.y + v.y * w.w;
#pragma unroll
    for (int off = 32; off > 0; off >>= 1) {
        a0 += __shfl_down(a0, off);
        a1 += __shfl_down(a1, off);
    }
    if (lane == 0) {
        out[(size_t)wid * 2]     = a0 + b3[0];
        out[(size_t)wid * 2 + 1] = a1 + b3[1];
    }
}

// ---------------------------------------------------------------------------
extern "C" void kernel_launch(void* const* d_in, const int* in_sizes, int n_in,
                              void* d_out, int out_size, void* d_ws, size_t ws_size,
                              hipStream_t stream) {
    const float* x   = (const float*)d_in[0];
    const int*   ei  = (const int*)d_in[1];
    const int*   src = ei;
    const int*   dst = ei + N_EDGES;
    const float* W1 = (const float*)d_in[2];
    const float* b1 = (const float*)d_in[3];
    const float* W2 = (const float*)d_in[4];
    const float* b2 = (const float*)d_in[5];
    const float* W3 = (const float*)d_in[6];
    const float* b3 = (const float*)d_in[7];
    float* out = (float*)d_out;

    char* base = (char*)d_ws;
    size_t off = 0;
    auto take = [&](size_t bytes) -> char* {
        char* p = base + off;
        off += (bytes + 255) & ~(size_t)255;
        return p;
    };
    int*            cnt    = (int*)           take(N_NODES * sizeof(int));
    unsigned short* bucket = (unsigned short*)take((size_t)N_NODES * CAP * sizeof(unsigned short));
    float*          y      = (float*)         take((size_t)N_NODES * F * sizeof(float));
    float*          h      = (float*)         take((size_t)N_NODES * F * sizeof(float));

    hipMemsetAsync(cnt, 0, N_NODES * sizeof(int), stream);

    // layer 1 GEMM (y = x@W1) overlapped with uint16 bucket build
    gemm_bucket_kernel<<<GEMM_BLOCKS + BUCKET_BLOCKS, 256, 0, stream>>>(
        x, W1, y, src, dst, cnt, bucket);
    // h = relu(mean(y) + b1)
    slice_agg_kernel<<<N_NODES / 2, 256, 0, stream>>>(y, cnt, bucket, b1, h);
    // y = h @ W2
    gemm_kernel<<<N_NODES / 32, 256, 0, stream>>>(h, W2, y);
    // h = relu(mean(y) + b2)
    slice_agg_kernel<<<N_NODES / 2, 256, 0, stream>>>(y, cnt, bucket, b2, h);
    // out = h @ W3 + b3
    final_kernel<<<(N_NODES * 64) / 256, 256, 0, stream>>>(h, W3, b3, out);
}

// Round 11
// 185.928 us; speedup vs baseline: 1.1163x; 1.0077x over previous
//
#include <hip/hip_runtime.h>

#define N_NODES 20000
#define N_EDGES 640000
#define F 128
#define CAP 128          // max in-degree; deg ~ Binomial(640K, 1/20K); expected max deg ~57
#define GEMM_BLOCKS (N_NODES / 32)     // 625
#define SCAT_BLOCKS 2560               // 320 per XCD residue class
#define SCAT_STRIDE (SCAT_BLOCKS / 8 * 256)   // 81920 edges per sweep per class
#define NODES_PER_XCD (N_NODES / 8)    // 2500

// HISTORY:
//  r2/r3: fused GEMM+proj epilogue spilled (64-VGPR cap; VGPR=256 + 565 MB scratch).
//  r4: de-fused: 218. r5: gather-into-GEMM fusion -> occ 22.6%: 227 (revert).
//  r6: mean-linearity reorder (GEMM first): 215. r7: gemm1+bucket merge: 213.
//  r8: uint16 bucket + slice-partitioned agg (4 x 32-float slices, bid%8 XCD swizzle): 203.
//  r9: proj fused into agg2 via atomicAdd: 207.5 (regression, REVERTED).
//  r10: register-held index lists (shfl-distributed) + 2 nodes/wave agg: 187.4.
//  r11: XCD-LOCAL SCATTER. r10 counters: bucket scatter wrote 44.6 MB HBM for a
//       5.1 MB payload (random 2B stores -> partial-line writeback churn).
//       Partition dst-nodes into 8 ranges of 2500 (640 KB bucket region each,
//       fits one XCD L2); scatter blocks grouped by bid&7 scan the whole edge
//       list but only scatter their own range -> each line dirtied by one XCD,
//       written back once. Partition is by ADDRESS, so correctness never
//       depends on the bid%8->XCD heuristic.

// ---------------------------------------------------------------------------
// Merged: blocks [0,625) y = A @ W (proven 44-VGPR tile); blocks [625,3185)
// XCD-local scatter of edges into per-destination uint16 buckets.
// ---------------------------------------------------------------------------
__global__ __launch_bounds__(256)
void gemm_bucket_kernel(const float* __restrict__ A, const float* __restrict__ W,
                        float* __restrict__ C,
                        const int* __restrict__ src, const int* __restrict__ dst,
                        int* __restrict__ cnt, unsigned short* __restrict__ bucket) {
    __shared__ float As[32][F + 4];
    int tid = threadIdx.x;
    int bid = blockIdx.x;

    if (bid >= GEMM_BLOCKS) {
        int s   = bid - GEMM_BLOCKS;   // 0..2559
        int g   = bid & 7;             // XCD residue of the RAW block id
        int idx = s >> 3;              // 0..319 within this residue class
        int lo  = g * NODES_PER_XCD;
        int hi  = lo + NODES_PER_XCD;
        for (int e = idx * 256 + tid; e < N_EDGES; e += SCAT_STRIDE) {
            int d  = dst[e];           // coalesced
            int sv = src[e];           // coalesced
            if (d >= lo && d < hi) {   // ~1/8 of lanes active
                int pos = atomicAdd(&cnt[d], 1);
                if (pos < CAP) bucket[(size_t)d * CAP + pos] = (unsigned short)sv;
            }
        }
        return;
    }

    int row0 = bid * 32;
    const float4* A4 = (const float4*)(A + (size_t)row0 * F);
    for (int i = tid; i < 32 * 32; i += 256) {
        float4 v = A4[i];
        int r = i >> 5, c4 = (i & 31) * 4;
        *(float4*)&As[r][c4] = v;
    }
    __syncthreads();

    int tx = tid & 31, ty = tid >> 5;
    int c0 = tx * 4, r0 = ty * 4;
    float acc[4][4] = {};

    for (int k = 0; k < F; k += 4) {
        float4 a4[4];
#pragma unroll
        for (int i = 0; i < 4; ++i) a4[i] = *(const float4*)&As[r0 + i][k];
#pragma unroll
        for (int u = 0; u < 4; ++u) {
            float4 w = *(const float4*)(W + (size_t)(k + u) * F + c0);
#pragma unroll
            for (int i = 0; i < 4; ++i) {
                float a = (u == 0) ? a4[i].x : (u == 1) ? a4[i].y : (u == 2) ? a4[i].z : a4[i].w;
                acc[i][0] += a * w.x;
                acc[i][1] += a * w.y;
                acc[i][2] += a * w.z;
                acc[i][3] += a * w.w;
            }
        }
    }

#pragma unroll
    for (int i = 0; i < 4; ++i) {
        float4 o;
        o.x = acc[i][0]; o.y = acc[i][1]; o.z = acc[i][2]; o.w = acc[i][3];
        *(float4*)(C + (size_t)(row0 + r0 + i) * F + c0) = o;
    }
}

// ---------------------------------------------------------------------------
// Plain GEMM (layer 2): C = A @ W.
// ---------------------------------------------------------------------------
__global__ __launch_bounds__(256)
void gemm_kernel(const float* __restrict__ A, const float* __restrict__ W,
                 float* __restrict__ C) {
    __shared__ float As[32][F + 4];
    int tid  = threadIdx.x;
    int row0 = blockIdx.x * 32;

    const float4* A4 = (const float4*)(A + (size_t)row0 * F);
    for (int i = tid; i < 32 * 32; i += 256) {
        float4 v = A4[i];
        int r = i >> 5, c4 = (i & 31) * 4;
        *(float4*)&As[r][c4] = v;
    }
    __syncthreads();

    int tx = tid & 31, ty = tid >> 5;
    int c0 = tx * 4, r0 = ty * 4;
    float acc[4][4] = {};

    for (int k = 0; k < F; k += 4) {
        float4 a4[4];
#pragma unroll
        for (int i = 0; i < 4; ++i) a4[i] = *(const float4*)&As[r0 + i][k];
#pragma unroll
        for (int u = 0; u < 4; ++u) {
            float4 w = *(const float4*)(W + (size_t)(k + u) * F + c0);
#pragma unroll
            for (int i = 0; i < 4; ++i) {
                float a = (u == 0) ? a4[i].x : (u == 1) ? a4[i].y : (u == 2) ? a4[i].z : a4[i].w;
                acc[i][0] += a * w.x;
                acc[i][1] += a * w.y;
                acc[i][2] += a * w.z;
                acc[i][3] += a * w.w;
            }
        }
    }

#pragma unroll
    for (int i = 0; i < 4; ++i) {
        float4 o;
        o.x = acc[i][0]; o.y = acc[i][1]; o.z = acc[i][2]; o.w = acc[i][3];
        *(float4*)(C + (size_t)(row0 + r0 + i) * F + c0) = o;
    }
}

// ---------------------------------------------------------------------------
// One node-slice gather with indices held in registers (packed = 2 u16/lane,
// lane l holds list positions 2l, 2l+1). Position p=(c<<3)+r lives in word
// p>>1 = (c<<2)+(r>>1), half p&1 = r&1. All shfls execute with full exec
// mask (deg is wave-uniform; tail shfl hoisted before the divergent guard).
// ---------------------------------------------------------------------------
__device__ __forceinline__ float4 slice_gather(const float4* __restrict__ fb,
                                               int packed, int deg, int r) {
    float4 acc; acc.x = acc.y = acc.z = acc.w = 0.f;
    int nchunks = deg >> 3;        // full 8-neighbor chunks
    int sh  = r >> 1;
    int sel = r & 1;
    int c = 0;
    for (; c + 4 <= nchunks; c += 4) {
        int w0 = __shfl(packed, (c << 2) + sh);
        int w1 = __shfl(packed, ((c + 1) << 2) + sh);
        int w2 = __shfl(packed, ((c + 2) << 2) + sh);
        int w3 = __shfl(packed, ((c + 3) << 2) + sh);
        int i0 = sel ? ((w0 >> 16) & 0xffff) : (w0 & 0xffff);
        int i1 = sel ? ((w1 >> 16) & 0xffff) : (w1 & 0xffff);
        int i2 = sel ? ((w2 >> 16) & 0xffff) : (w2 & 0xffff);
        int i3 = sel ? ((w3 >> 16) & 0xffff) : (w3 & 0xffff);
        float4 v0 = fb[(size_t)i0 * 32];
        float4 v1 = fb[(size_t)i1 * 32];
        float4 v2 = fb[(size_t)i2 * 32];
        float4 v3 = fb[(size_t)i3 * 32];
        acc.x += (v0.x + v1.x) + (v2.x + v3.x);
        acc.y += (v0.y + v1.y) + (v2.y + v3.y);
        acc.z += (v0.z + v1.z) + (v2.z + v3.z);
        acc.w += (v0.w + v1.w) + (v2.w + v3.w);
    }
    for (; c < nchunks; ++c) {
        int w = __shfl(packed, (c << 2) + sh);
        int idx = sel ? ((w >> 16) & 0xffff) : (w & 0xffff);
        float4 v = fb[(size_t)idx * 32];
        acc.x += v.x; acc.y += v.y; acc.z += v.z; acc.w += v.w;
    }
    int wt = __shfl(packed, (nchunks << 2) + sh);   // hoisted: full exec mask
    if (r < (deg & 7)) {
        int idx = sel ? ((wt >> 16) & 0xffff) : (wt & 0xffff);
        float4 v = fb[(size_t)idx * 32];
        acc.x += v.x; acc.y += v.y; acc.z += v.z; acc.w += v.w;
    }
    return acc;
}

// ---------------------------------------------------------------------------
// Slice-partitioned gather + bias + relu, TWO nodes per wave:
//   out[n, slice] = relu(mean_{j in nbrs(n)} y[j, slice] + b[slice])
// Grid 10000 x 256. g = bid%8 -> XCD heuristic; slice = g&3 (2.56 MB slice
// fits the 4 MB XCD L2). Wave = 8 rows x 8 float4-cols per gather instr.
// ---------------------------------------------------------------------------
__global__ __launch_bounds__(256)
void slice_agg_kernel(const float* __restrict__ y, const int* __restrict__ cnt,
                      const unsigned short* __restrict__ bucket,
                      const float* __restrict__ b, float* __restrict__ out) {
    int bid   = blockIdx.x;
    int g     = bid & 7;
    int i     = bid >> 3;          // 0..1249
    int slice = g & 3;
    int jj    = i * 2 + (g >> 2);  // 0..2499
    int wave  = threadIdx.x >> 6;
    int lane  = threadIdx.x & 63;
    int node0 = jj * 8 + wave * 2;
    int node1 = node0 + 1;
    int r     = lane >> 3;
    int c4    = lane & 7;

    int deg0 = cnt[node0];
    int deg1 = cnt[node1];
    const unsigned short* lst0 = bucket + (size_t)node0 * CAP;
    const unsigned short* lst1 = bucket + (size_t)node1 * CAP;
    int packed0 = *(const int*)(lst0 + 2 * lane);
    int packed1 = *(const int*)(lst1 + 2 * lane);

    const float4* fb = (const float4*)y + slice * 8 + c4;   // row stride 32 float4

    int d0 = deg0 < CAP ? deg0 : CAP;
    int d1 = deg1 < CAP ? deg1 : CAP;
    float4 a0 = slice_gather(fb, packed0, d0, r);
    float4 a1 = slice_gather(fb, packed1, d1, r);

#pragma unroll
    for (int off = 8; off < 64; off <<= 1) {
        a0.x += __shfl_xor(a0.x, off);
        a0.y += __shfl_xor(a0.y, off);
        a0.z += __shfl_xor(a0.z, off);
        a0.w += __shfl_xor(a0.w, off);
        a1.x += __shfl_xor(a1.x, off);
        a1.y += __shfl_xor(a1.y, off);
        a1.z += __shfl_xor(a1.z, off);
        a1.w += __shfl_xor(a1.w, off);
    }

    if (r == 0) {   // lanes 0..7: lane == c4
        float4 bv = ((const float4*)b)[slice * 8 + c4];
        float inv0 = 1.0f / fmaxf((float)deg0, 1.0f);
        float4 o0;
        o0.x = fmaxf(a0.x * inv0 + bv.x, 0.f);
        o0.y = fmaxf(a0.y * inv0 + bv.y, 0.f);
        o0.z = fmaxf(a0.z * inv0 + bv.z, 0.f);
        o0.w = fmaxf(a0.w * inv0 + bv.w, 0.f);
        ((float4*)out)[(size_t)node0 * 32 + slice * 8 + c4] = o0;
        float inv1 = 1.0f / fmaxf((float)deg1, 1.0f);
        float4 o1;
        o1.x = fmaxf(a1.x * inv1 + bv.x, 0.f);
        o1.y = fmaxf(a1.y * inv1 + bv.y, 0.f);
        o1.z = fmaxf(a1.z * inv1 + bv.z, 0.f);
        o1.w = fmaxf(a1.w * inv1 + bv.w, 0.f);
        ((float4*)out)[(size_t)node1 * 32 + slice * 8 + c4] = o1;
    }
}

// ---------------------------------------------------------------------------
// out[N x 2] = h[N x 128] @ W3[128 x 2] + b3. One wave per node, shuffle
// reduce. Proven cheap (never in any top-5).
// ---------------------------------------------------------------------------
__global__ __launch_bounds__(256)
void final_kernel(const float* __restrict__ h, const float* __restrict__ W3,
                  const float* __restrict__ b3, float* __restrict__ out) {
    int wid  = (blockIdx.x * blockDim.x + threadIdx.x) >> 6;
    int lane = threadIdx.x & 63;
    if (wid >= N_NODES) return;
    float2 v = ((const float2*)h)[(size_t)wid * 64 + lane];
    float4 w = ((const float4*)W3)[lane];
    float a0 = v.x * w.x + v.y * w.z;
    float a1 = v.x * w.y + v.y * w.w;
#pragma unroll
    for (int off = 32; off > 0; off >>= 1) {
        a0 += __shfl_down(a0, off);
        a1 += __shfl_down(a1, off);
    }
    if (lane == 0) {
        out[(size_t)wid * 2]     = a0 + b3[0];
        out[(size_t)wid * 2 + 1] = a1 + b3[1];
    }
}

// ---------------------------------------------------------------------------
extern "C" void kernel_launch(void* const* d_in, const int* in_sizes, int n_in,
                              void* d_out, int out_size, void* d_ws, size_t ws_size,
                              hipStream_t stream) {
    const float* x   = (const float*)d_in[0];
    const int*   ei  = (const int*)d_in[1];
    const int*   src = ei;
    const int*   dst = ei + N_EDGES;
    const float* W1 = (const float*)d_in[2];
    const float* b1 = (const float*)d_in[3];
    const float* W2 = (const float*)d_in[4];
    const float* b2 = (const float*)d_in[5];
    const float* W3 = (const float*)d_in[6];
    const float* b3 = (const float*)d_in[7];
    float* out = (float*)d_out;

    char* base = (char*)d_ws;
    size_t off = 0;
    auto take = [&](size_t bytes) -> char* {
        char* p = base + off;
        off += (bytes + 255) & ~(size_t)255;
        return p;
    };
    int*            cnt    = (int*)           take(N_NODES * sizeof(int));
    unsigned short* bucket = (unsigned short*)take((size_t)N_NODES * CAP * sizeof(unsigned short));
    float*          y      = (float*)         take((size_t)N_NODES * F * sizeof(float));
    float*          h      = (float*)         take((size_t)N_NODES * F * sizeof(float));

    hipMemsetAsync(cnt, 0, N_NODES * sizeof(int), stream);

    // layer 1 GEMM (y = x@W1) overlapped with XCD-local uint16 bucket build
    gemm_bucket_kernel<<<GEMM_BLOCKS + SCAT_BLOCKS, 256, 0, stream>>>(
        x, W1, y, src, dst, cnt, bucket);
    // h = relu(mean(y) + b1)
    slice_agg_kernel<<<N_NODES / 2, 256, 0, stream>>>(y, cnt, bucket, b1, h);
    // y = h @ W2
    gemm_kernel<<<N_NODES / 32, 256, 0, stream>>>(h, W2, y);
    // h = relu(mean(y) + b2)
    slice_agg_kernel<<<N_NODES / 2, 256, 0, stream>>>(y, cnt, bucket, b2, h);
    // out = h @ W3 + b3
    final_kernel<<<(N_NODES * 64) / 256, 256, 0, stream>>>(h, W3, b3, out);
}